// Round 16
// baseline (127.015 us; speedup 1.0000x reference)
//
#include <hip/hip_runtime.h>
#include <cstdint>

// ---------------------------------------------------------------------------
// GQA cross-attention, bf16-MFMA pipeline (4 dispatches):
//   prep_k   : X,E -> bf16 casts ; Wq,Wo,Wk|Wv -> transposed bf16
//   qkv_k    : Q-proj (+RoPE, *0.125*log2e -> Qb) and KV-proj (K+RoPE -> Kb,
//              V -> transposed Vt); 128x128 tile, BK=32, paired-row swizzled
//              LDS (32KB dbuf), 2-phase pipeline
//   attn_k   : flash attention, 16 waves x 16 q-rows (1024 thr, grid 256),
//              dbuf K/V split staging, log2 softmax, l-sum via ones-MFMA.
//              CLOSED lines: no-max softmax (r8/9); 32 q/wave (r5/r14);
//              counted-vmcnt attn (r11 null) / GEMM (r12 TLP regression).
//   oproj_k  : O-projection, f32 out
// ---------------------------------------------------------------------------

typedef __bf16 bf16x8 __attribute__((ext_vector_type(8)));
typedef __bf16 bf16x4v __attribute__((ext_vector_type(4)));
typedef float f32x4 __attribute__((ext_vector_type(4)));

#define MFMA16(a, b, c) __builtin_amdgcn_mfma_f32_16x16x32_bf16((a), (b), (c), 0, 0, 0)

constexpr int Bc = 2, TQc = 2048, TKc = 2048, Dc = 1024, Hc = 16, Gc = 4, HDc = 64;
constexpr float QSCALE = 0.18033688011112042f;  // 0.125 * log2(e): log2-domain scores

__device__ __forceinline__ ushort bfbits(float x) {  // native RNE f32->bf16
  __bf16 h = (__bf16)x;
  return __builtin_bit_cast(ushort, h);
}

__device__ __forceinline__ float fexp2(float x) {  // raw v_exp_f32: D = 2^S0
  float r;
  asm("v_exp_f32 %0, %1" : "=v"(r) : "v"(x));
  return r;
}

__device__ __forceinline__ float fmax3(float a, float b, float c) {
  return fmaxf(fmaxf(a, b), c);  // clang fuses to v_max3_f32 on gfx9+
}

__device__ __forceinline__ void async_lds16(void* lds, const void* g) {
  // wave-uniform LDS base; lane i lands at base + 16*i (guide §5)
  __builtin_amdgcn_global_load_lds((const __attribute__((address_space(1))) uint32_t*)g,
                                   (__attribute__((address_space(3))) uint32_t*)lds,
                                   16, 0, 0);
}

// ---------------- prep: casts (8192 blocks) + weight transposes (768) ------
__global__ __launch_bounds__(256) void prep_k(const float* __restrict__ X,
                                              const float* __restrict__ E,
                                              const float* __restrict__ Wq,
                                              const float* __restrict__ Wo,
                                              const float* __restrict__ Wk,
                                              const float* __restrict__ Wv,
                                              ushort* __restrict__ Xb,
                                              ushort* __restrict__ Eb,
                                              ushort* __restrict__ Wqt,
                                              ushort* __restrict__ Wot,
                                              ushort* __restrict__ Wkvt) {
  __shared__ float t[64][65];
  const int bid = blockIdx.x;
  if (bid < 8192) {  // cast: 4096 blocks X, 4096 blocks E
    const float* s = (bid < 4096) ? X : E;
    ushort* d = (bid < 4096) ? Xb : Eb;
    int i = (bid & 4095) * 256 + threadIdx.x;
    float4 v = reinterpret_cast<const float4*>(s)[i];
    ushort4 o;
    o.x = bfbits(v.x); o.y = bfbits(v.y); o.z = bfbits(v.z); o.w = bfbits(v.w);
    reinterpret_cast<ushort4*>(d)[i] = o;
    return;
  }
  // weight transpose: W[R][C] f32 -> Wt[C][R] bf16 (R = 1024 always)
  const int w = bid - 8192;           // [0, 768)
  const int z = w >> 8, rem = w & 255;
  const int bx = rem & 15, by = rem >> 4;
  const float* src;
  ushort* dst;
  int C, c0;
  if (z == 0)      { src = Wq; dst = Wqt; C = 1024; c0 = bx * 64; }
  else if (z == 1) { src = Wo; dst = Wot; C = 1024; c0 = bx * 64; }
  else {
    if (bx >= 8) return;
    if (bx < 4) { src = Wk; dst = Wkvt; }
    else        { src = Wv; dst = Wkvt + 256 * 1024; }
    C = 256; c0 = (bx & 3) * 64;
  }
  const int r0 = by * 64;
  const int tx = threadIdx.x & 63, ty = threadIdx.x >> 6;
#pragma unroll
  for (int i = 0; i < 16; ++i) {
    int r = i * 4 + ty;
    t[r][tx] = src[(size_t)(r0 + r) * C + c0 + tx];
  }
  __syncthreads();
#pragma unroll
  for (int i = 0; i < 16; ++i) {
    int c = i * 4 + ty;
    dst[(size_t)(c0 + c) * 1024 + r0 + tx] = bfbits(t[tx][c]);
  }
}

// ------- GEMM mainloop: 128x128 tile, BK=32, 2-phase double-buffered -------
// Paired-row LDS layout: prow p (128B) holds logical rows {2p, 2p+1}; 16B
// slot s stores logical chunk c = s ^ (p&7)  (c = (row&1)*4 + k16).
// Read check: an l4-group's 16 lanes hit 8 distinct slots x 2 addrs = 2-way
// conflict (free, m136).  Linear LDS dest + pre-swizzled global src (rule
// #21).  LDS = 2 x (8K A + 8K B) = 32KB.  One barrier per K-step.
__device__ __forceinline__ void gemm_mainloop(const ushort* __restrict__ A,
                                              const ushort* __restrict__ Bt,
                                              int m0, int n0, int K,
                                              char* smem, f32x4 acc[4][4]) {
  const int lane = threadIdx.x & 63, wid = threadIdx.x >> 6;
  const int l15 = lane & 15, l4 = lane >> 4;
  const int wr = (wid >> 1) * 64, wc = (wid & 1) * 64;
  // staging decode: within a 1KB chunk, lane -> prow sp8, swizzled slot -> c
  const int sp8 = lane >> 3;                  // prow within chunk (0..7)
  const int scl = (lane & 7) ^ sp8;           // logical chunk at this slot
  const int slr = 2 * sp8 + (scl >> 2);       // logical row within chunk's 16
  const int sko = (scl & 3) * 8;              // k offset (ushort)

  char* bufA[2] = {smem, smem + 8192};
  char* bufB[2] = {smem + 16384, smem + 24576};

  const int nsteps = K >> 5;
  auto stage = [&](int step, int bi) {  // 4 loads/wave: 2 A-chunks + 2 B-chunks
    const int k0 = step * 32;
#pragma unroll
    for (int j = 0; j < 2; ++j) {
      const int i = wid * 2 + j;        // 1KB chunk (8 per 8KB tile)
      const int lr = i * 16 + slr;      // logical tile row
      async_lds16(bufA[bi] + i * 1024, A + (size_t)(m0 + lr) * K + k0 + sko);
      async_lds16(bufB[bi] + i * 1024, Bt + (size_t)(n0 + lr) * K + k0 + sko);
    }
  };

  stage(0, 0);
  __syncthreads();
  int buf = 0;
  for (int s2 = 0; s2 < nsteps; ++s2) {
    if (s2 + 1 < nsteps) stage(s2 + 1, buf ^ 1);  // WAR-safe: read in s2-1
    const char* aB = bufA[buf];
    const char* bB = bufB[buf];
    bf16x8 af[4], bfr[4];
#pragma unroll
    for (int mi = 0; mi < 4; ++mi) {
      const int R = wr + mi * 16 + l15;
      const int p = R >> 1;
      const int sl = (((R & 1) << 2) | l4) ^ (p & 7);
      af[mi] = *reinterpret_cast<const bf16x8*>(aB + p * 128 + (sl << 4));
    }
#pragma unroll
    for (int ni = 0; ni < 4; ++ni) {
      const int R = wc + ni * 16 + l15;
      const int p = R >> 1;
      const int sl = (((R & 1) << 2) | l4) ^ (p & 7);
      bfr[ni] = *reinterpret_cast<const bf16x8*>(bB + p * 128 + (sl << 4));
    }
#pragma unroll
    for (int mi = 0; mi < 4; ++mi)
#pragma unroll
      for (int ni = 0; ni < 4; ++ni)
        acc[mi][ni] = MFMA16(af[mi], bfr[ni], acc[mi][ni]);
    __syncthreads();  // staged step landed; all waves done reading buf
    buf ^= 1;
  }
}

// ------- shared GEMM epilogue.  mode 0: f32 C+bias. mode 1: Q+RoPE+scale.
// mode 2: N=512, col<256 K+RoPE; col>=256 V -> transposed Vt. --------------
__device__ __forceinline__ void gemm_epilogue(f32x4 acc[4][4], int mode, int m0,
                                              int n0, const float* b0,
                                              const float* b1, float* Cf,
                                              ushort* U0, ushort* U1, int N) {
  const int lane = threadIdx.x & 63, wid = threadIdx.x >> 6;
  const int l15 = lane & 15, l4 = lane >> 4;
  const int wr = (wid >> 1) * 64, wc = (wid & 1) * 64;
#pragma unroll
  for (int ni = 0; ni < 4; ++ni) {
    const int col = n0 + wc + ni * 16 + l15;
    if (mode == 0) {
      const float bv = b0[col];
#pragma unroll
      for (int mi = 0; mi < 4; ++mi) {
        const int rowb = m0 + wr + mi * 16 + l4 * 4;
#pragma unroll
        for (int r = 0; r < 4; ++r)
          Cf[(size_t)(rowb + r) * N + col] = acc[mi][ni][r] + bv;
      }
    } else if (mode == 1) {
      const int h = col >> 6, d = col & 63, fi = d >> 1, odd = d & 1;
      const float div = __expf(-0.28782313662425572f * (float)fi);  // -ln(1e4)/32
      const float bv = b0[col];
#pragma unroll
      for (int mi = 0; mi < 4; ++mi) {
        const int rowb = m0 + wr + mi * 16 + l4 * 4;
#pragma unroll
        for (int r = 0; r < 4; ++r) {
          const int row = rowb + r, b = row >> 11, t = row & 2047;
          const float val = acc[mi][ni][r] + bv;
          const float prt = __shfl_xor(val, 1);  // partner column (d^1)
          float sn, cs;
          __sincosf((float)t * div, &sn, &cs);
          const float o = odd ? (prt * sn + val * cs) : (val * cs - prt * sn);
          U0[(((size_t)(b * Hc + h)) * TQc + t) * HDc + d] = bfbits(o * QSCALE);
        }
      }
    } else {
      if (col < 256) {  // K path: RoPE -> Kb[b][g][t][d]
        const int g = col >> 6, d = col & 63, fi = d >> 1, odd = d & 1;
        const float div = __expf(-0.28782313662425572f * (float)fi);
        const float bv = b0[col];
#pragma unroll
        for (int mi = 0; mi < 4; ++mi) {
          const int rowb = m0 + wr + mi * 16 + l4 * 4;
#pragma unroll
          for (int r = 0; r < 4; ++r) {
            const int row = rowb + r, b = row >> 11, t = row & 2047;
            const float val = acc[mi][ni][r] + bv;
            const float prt = __shfl_xor(val, 1);
            float sn, cs;
            __sincosf((float)t * div, &sn, &cs);
            const float o = odd ? (prt * sn + val * cs) : (val * cs - prt * sn);
            U0[(((size_t)(b * Gc + g)) * TKc + t) * HDc + d] = bfbits(o);
          }
        }
      } else {  // V path: transpose-write Vt[b][g][d][t]
        const int c2 = col - 256;
        const int g = c2 >> 6, d = c2 & 63;
        const float bv = b1[c2];
#pragma unroll
        for (int mi = 0; mi < 4; ++mi) {
          const int rowb = m0 + wr + mi * 16 + l4 * 4;
          const int b = rowb >> 11, t0 = rowb & 2047;
          ushort4 w;
          w.x = bfbits(acc[mi][ni][0] + bv);
          w.y = bfbits(acc[mi][ni][1] + bv);
          w.z = bfbits(acc[mi][ni][2] + bv);
          w.w = bfbits(acc[mi][ni][3] + bv);
          *reinterpret_cast<ushort4*>(
              &U1[(((size_t)(b * Gc + g)) * HDc + d) * TKc + t0]) = w;
        }
      }
    }
  }
}

// ------- Q-proj (blocks 0..255) + KV-proj (256..383), one launch -----------
__global__ __launch_bounds__(256) void qkv_k(const ushort* __restrict__ Xb,
                                             const ushort* __restrict__ Eb,
                                             const ushort* __restrict__ Wqt,
                                             const ushort* __restrict__ Wkvt,
                                             const float* __restrict__ bq,
                                             const float* __restrict__ bk,
                                             const float* __restrict__ bv,
                                             ushort* __restrict__ Qb,
                                             ushort* __restrict__ Kb,
                                             ushort* __restrict__ Vt) {
  __shared__ __attribute__((aligned(16))) char smem[32 * 1024];
  const int bid = blockIdx.x;
  const ushort *A, *Bt;
  const float *b0, *b1 = nullptr;
  ushort *U0, *U1 = nullptr;
  int mode, tb, tn;
  if (bid < 256) { A = Xb; Bt = Wqt; b0 = bq; U0 = Qb; mode = 1; tb = bid; tn = 8; }
  else { A = Eb; Bt = Wkvt; b0 = bk; b1 = bv; U0 = Kb; U1 = Vt; mode = 2; tb = bid - 256; tn = 4; }
  const int m0 = (tb / tn) * 128, n0 = (tb % tn) * 128;
  const f32x4 z = {0.f, 0.f, 0.f, 0.f};
  f32x4 acc[4][4];
#pragma unroll
  for (int mi = 0; mi < 4; ++mi)
#pragma unroll
    for (int ni = 0; ni < 4; ++ni) acc[mi][ni] = z;
  gemm_mainloop(A, Bt, m0, n0, 1024, smem, acc);
  gemm_epilogue(acc, mode, m0, n0, b0, b1, nullptr, U0, U1, 0);
}

// ------- O-projection: out = Ob * Wot^T + bo (f32) -------------------------
__global__ __launch_bounds__(256) void oproj_k(const ushort* __restrict__ Ob,
                                               const ushort* __restrict__ Wot,
                                               const float* __restrict__ bo,
                                               float* __restrict__ out) {
  __shared__ __attribute__((aligned(16))) char smem[32 * 1024];
  const int bid = blockIdx.x;
  const int m0 = (bid >> 3) * 128, n0 = (bid & 7) * 128;
  const f32x4 z = {0.f, 0.f, 0.f, 0.f};
  f32x4 acc[4][4];
#pragma unroll
  for (int mi = 0; mi < 4; ++mi)
#pragma unroll
    for (int ni = 0; ni < 4; ++ni) acc[mi][ni] = z;
  gemm_mainloop(Ob, Wot, m0, n0, 1024, smem, acc);
  gemm_epilogue(acc, 0, m0, n0, bo, nullptr, out, nullptr, nullptr, 1024);
}

// ------- flash attention, LDS-staged K/V, swapped-QK^T, log2 softmax -------
// Qb[b][h][t][64] (pre-scaled by 0.125*log2e), Kb[b][g][t][64], Vt[b][g][64][t].
// 1024 thr = 16 waves x 16 q-rows (256 q-rows/block), KVBLK=64, grid 256.
// Decode: bid&7 = (b,g); pos = bid>>3 in 0..31; h = g*4 + (pos>>3);
//         q0 = (pos&7)*256 + wid*16  (max 7*256+15*16+16 = 2048, exact).
// Double-buffered K/V, SPLIT staging: waves 0-7 stage K rows (wid&7)*8..+7,
// waves 8-15 stage V rows likewise -> 1 global_load_lds per wave per tile.
// l-sum via ones-MFMA: acc1 = P·1 lands in the epilogue row layout.
__global__ __launch_bounds__(1024, 4) void attn_k(const ushort* __restrict__ Qg,
                                                  const ushort* __restrict__ Kg,
                                                  const ushort* __restrict__ Vg,
                                                  ushort* __restrict__ Ob) {
  __shared__ __attribute__((aligned(16))) char smem[64 * 1024];
  const int lane = threadIdx.x & 63, wid = threadIdx.x >> 6;  // wid 0..15
  const int l15 = lane & 15, l4 = lane >> 4;
  // XCD-aware decode: bid&7 = (b,g) group -> each XCD L2 caches ONE group's K/V
  const int bid = blockIdx.x;  // 256 blocks
  const int bg = bid & 7, pos = bid >> 3;      // pos 0..31
  const int b = bg >> 2, g = bg & 3;
  const int h = g * 4 + (pos >> 3);            // 4 heads per group
  const int q0 = (pos & 7) * 256 + wid * 16;   // 16 q-rows per wave
  const ushort* Qp = Qg + ((size_t)(b * Hc + h)) * TQc * HDc;
  const ushort* Kp = Kg + ((size_t)(b * Gc + g)) * TKc * HDc;
  const ushort* Vp = Vg + ((size_t)(b * Gc + g)) * HDc * TKc;
  // LDS map: K dbuf [2][8192], V dbuf [2][8192], P [16][2048]
  char* sK = smem;                          // 0   .. 16K
  char* sV = smem + 16384;                  // 16K .. 32K
  char* pb = smem + 32768 + wid * 2048;     // per-wave P tile [16][64] bf16
  const int rx = (l15 & 7) << 4;            // P-row swizzle
  const int swz = l15 & 7;                  // K/V fragment chunk swizzle

  // staging: waves 0-7 stage K (1KB each), waves 8-15 stage V (1KB each)
  const int wkv = wid & 7;
  const int sr = wkv * 8 + (lane >> 3);              // tile row this lane fills
  const int sc = (lane & 7) ^ ((lane >> 3) & 7);     // pre-swizzled src chunk
  const bool isK = (wid < 8);                        // wave-uniform
  const char* srcN = isK ? (const char*)Kp + (size_t)sr * 128 + sc * 16
                         : (const char*)Vp + (size_t)sr * (TKc * 2) + sc * 16;
  const size_t srcStep = isK ? 8192 : 128;
  char* dstBase = (isK ? sK : sV) + wkv * 1024;

  // Q (B operand): col n=l15 -> q=q0+l15, k=l4*8+j -> d
  bf16x8 bq0 = *reinterpret_cast<const bf16x8*>(Qp + (size_t)(q0 + l15) * HDc + l4 * 8);
  bf16x8 bq1 = *reinterpret_cast<const bf16x8*>(Qp + (size_t)(q0 + l15) * HDc + 32 + l4 * 8);

  bf16x8 vones;
#pragma unroll
  for (int i = 0; i < 8; ++i) vones[i] = (__bf16)1.0f;

  float m = -INFINITY;
  const f32x4 z = {0.f, 0.f, 0.f, 0.f};
  f32x4 accO[4] = {z, z, z, z};
  f32x4 acc1 = z;  // softmax denominator: rows q=l4*4+r, all cols equal

  constexpr int NT = TKc / 64;
  // prologue: stage tile 0 into buffer 0
  async_lds16(dstBase, srcN);
  srcN += srcStep;
  __syncthreads();

  int buf = 0;
  for (int kt = 0; kt < NT; ++kt) {
    if (kt + 1 < NT) {  // issue next-tile load; completes under compute
      async_lds16(dstBase + (buf ^ 1) * 8192, srcN);
      srcN += srcStep;
    }
    const char* sKb = sK + buf * 8192;
    const char* sVb = sV + buf * 8192;

    // QK^T: A = K[key=nf*16+l15][d], B = Q -> S^T[key][q=l15]  (log2 domain)
    f32x4 s[4] = {z, z, z, z};
#pragma unroll
    for (int nf = 0; nf < 4; ++nf) {
      const char* krow = sKb + (nf * 16 + l15) * 128;
      bf16x8 kf0 = *reinterpret_cast<const bf16x8*>(krow + ((l4 ^ swz) << 4));
      bf16x8 kf1 = *reinterpret_cast<const bf16x8*>(krow + (((4 + l4) ^ swz) << 4));
      s[nf] = MFMA16(kf0, bq0, s[nf]);
      s[nf] = MFMA16(kf1, bq1, s[nf]);
    }
    // V fragments from LDS: B[k=key][n=d]:  va[df][kk] = V^T tile row d
    bf16x8 va[4][2];
#pragma unroll
    for (int df = 0; df < 4; ++df) {
      const char* vrow = sVb + (df * 16 + l15) * 128;
      va[df][0] = *reinterpret_cast<const bf16x8*>(vrow + ((l4 ^ swz) << 4));
      va[df][1] = *reinterpret_cast<const bf16x8*>(vrow + (((4 + l4) ^ swz) << 4));
    }

    // ---- lane-local softmax (one q-row per lane, log2 domain) ----
    float pm = fmax3(fmax3(s[0][0], s[0][1], s[0][2]),
                     fmax3(s[0][3], s[1][0], s[1][1]),
                     fmax3(s[1][2], s[1][3], s[2][0]));
    pm = fmax3(pm,
               fmax3(s[2][1], s[2][2], s[2][3]),
               fmax3(s[3][0], s[3][1], fmaxf(s[3][2], s[3][3])));
    pm = fmaxf(pm, __shfl_xor(pm, 16));
    pm = fmaxf(pm, __shfl_xor(pm, 32));
    if (!__all(pm - m <= 11.5f)) {  // T13 defer-max (log2 units)
      float mn = fmaxf(m, pm);
      float sc2 = fexp2(m - mn);
      m = mn;
      acc1 *= sc2;
#pragma unroll
      for (int df = 0; df < 4; ++df) accO[df] *= sc2;
    }
#pragma unroll
    for (int nf = 0; nf < 4; ++nf)
#pragma unroll
      for (int r = 0; r < 4; ++r)
        s[nf][r] = fexp2(s[nf][r] - m);

    // ---- P -> per-wave LDS (row q=l15): 4x ds_write_b64, swizzled ----
#pragma unroll
    for (int nf = 0; nf < 4; ++nf) {
      bf16x4v pv;
      pv[0] = (__bf16)s[nf][0];
      pv[1] = (__bf16)s[nf][1];
      pv[2] = (__bf16)s[nf][2];
      pv[3] = (__bf16)s[nf][3];
      *reinterpret_cast<uint2*>(pb + l15 * 128 + ((nf * 32 + l4 * 8) ^ rx)) =
          __builtin_bit_cast(uint2, pv);
    }
    asm volatile("" ::: "memory");  // order P writes before P reads (TBAA insurance)
    // ---- PV: A = P[q=l15][k=key], B = V^T[key][d]; plus l = P·1 ----
    bf16x8 ap0 = *reinterpret_cast<const bf16x8*>(pb + l15 * 128 + ((l4 * 16) ^ rx));
    bf16x8 ap1 = *reinterpret_cast<const bf16x8*>(pb + l15 * 128 + ((64 + l4 * 16) ^ rx));
#pragma unroll
    for (int df = 0; df < 4; ++df)
      accO[df] = MFMA16(ap1, va[df][1], MFMA16(ap0, va[df][0], accO[df]));
    acc1 = MFMA16(ap1, vones, MFMA16(ap0, vones, acc1));

    __syncthreads();  // drains vmcnt: next tile landed; all waves done reading
    buf ^= 1;
  }

  // epilogue: lane holds O[q=q0+l4*4+r][d=df*16+l15]; acc1[r] = l for same row
  float inv[4];
#pragma unroll
  for (int r = 0; r < 4; ++r) inv[r] = 1.f / acc1[r];
#pragma unroll
  for (int df = 0; df < 4; ++df)
#pragma unroll
    for (int r = 0; r < 4; ++r) {
      int row = q0 + l4 * 4 + r;
      int col = h * HDc + df * 16 + l15;
      Ob[((size_t)b * TQc + row) * Dc + col] = bfbits(accO[df][r] * inv[r]);
    }
}

// ---------------------------------------------------------------------------
extern "C" void kernel_launch(void* const* d_in, const int* in_sizes, int n_in,
                              void* d_out, int out_size, void* d_ws, size_t ws_size,
                              hipStream_t stream) {
  const float* X  = (const float*)d_in[0];
  const float* E  = (const float*)d_in[1];
  const float* Wq = (const float*)d_in[2];
  const float* bq = (const float*)d_in[3];
  const float* Wk = (const float*)d_in[4];
  const float* bk = (const float*)d_in[5];
  const float* Wv = (const float*)d_in[6];
  const float* bv = (const float*)d_in[7];
  const float* Wo = (const float*)d_in[8];
  const float* bo = (const float*)d_in[9];
  float* out = (float*)d_out;
  char* ws = (char*)d_ws;

  const size_t MB = 1ull << 20;
  if (ws_size < 42 * MB) return;  // tripwire: reproduces stub failure signature

  ushort* Xb   = (ushort*)(ws + 0 * MB);   // [4096][1024] bf16
  ushort* Eb   = (ushort*)(ws + 8 * MB);   // [4096][1024]
  ushort* Wqt  = (ushort*)(ws + 16 * MB);  // [1024][1024]
  ushort* Wkvt = (ushort*)(ws + 18 * MB);  // [512][1024] (Wk^T | Wv^T)
  ushort* Wot  = (ushort*)(ws + 19 * MB);  // [1024][1024]
  ushort* Qb   = (ushort*)(ws + 21 * MB);  // [2][16][2048][64]
  ushort* Kb   = (ushort*)(ws + 29 * MB);  // [2][4][2048][64]
  ushort* Vt   = (ushort*)(ws + 31 * MB);  // [2][4][64][2048]
  ushort* Ob   = (ushort*)(ws + 33 * MB);  // [2][2048][1024]

  // 1. casts + weight transposes
  prep_k<<<dim3(8960), 256, 0, stream>>>(X, E, Wq, Wo, Wk, Wv, Xb, Eb, Wqt, Wot, Wkvt);
  // 2. Q-proj (+RoPE+scale) and KV-proj (K+RoPE, V^T) concurrently
  qkv_k<<<dim3(384), 256, 0, stream>>>(Xb, Eb, Wqt, Wkvt, bq, bk, bv, Qb, Kb, Vt);
  // 3. attention -> Ob
  attn_k<<<dim3(256), dim3(1024), 0, stream>>>(Qb, Kb, Vt, Ob);
  // 4. output projection -> out (f32)
  oproj_k<<<dim3(256), 256, 0, stream>>>(Ob, Wot, bo, out);
}

// Round 17
// 95.041 us; speedup vs baseline: 1.3364x; 1.3364x over previous
//
#include <hip/hip_runtime.h>
#include <cstdint>

// ---------------------------------------------------------------------------
// GQA cross-attention, bf16-MFMA pipeline (4 dispatches):
//   prep_k   : X,E -> bf16 casts ; Wq,Wo,Wk|Wv -> transposed bf16
//   qkv_k    : Q-proj (+RoPE, *0.125*log2e -> Qb) and KV-proj (K+RoPE -> Kb,
//              V -> transposed Vt); 128x64 tile BK=64 2-phase dbuf (PROVEN
//              operating point — 128x128/BK=32 regressed r16: grid collapse
//              to 1 blk/CU + 2x barrier count; 3-buffer counted-vmcnt
//              regressed r12: TLP loss).  + XCD-aware block swizzle (T1).
//   attn_k   : flash attention, 16 waves x 16 q-rows (1024 thr, grid 256),
//              dbuf K/V split staging, log2 softmax, l-sum via ones-MFMA.
//              CLOSED lines: no-max softmax (r8/9); 32 q/wave (r5/r14);
//              counted-vmcnt attn (r11 null).
//   oproj_k  : O-projection, f32 out (+ XCD swizzle)
// ---------------------------------------------------------------------------

typedef __bf16 bf16x8 __attribute__((ext_vector_type(8)));
typedef __bf16 bf16x4v __attribute__((ext_vector_type(4)));
typedef float f32x4 __attribute__((ext_vector_type(4)));

#define MFMA16(a, b, c) __builtin_amdgcn_mfma_f32_16x16x32_bf16((a), (b), (c), 0, 0, 0)

constexpr int Bc = 2, TQc = 2048, TKc = 2048, Dc = 1024, Hc = 16, Gc = 4, HDc = 64;
constexpr float QSCALE = 0.18033688011112042f;  // 0.125 * log2(e): log2-domain scores

__device__ __forceinline__ ushort bfbits(float x) {  // native RNE f32->bf16
  __bf16 h = (__bf16)x;
  return __builtin_bit_cast(ushort, h);
}

__device__ __forceinline__ float fexp2(float x) {  // raw v_exp_f32: D = 2^S0
  float r;
  asm("v_exp_f32 %0, %1" : "=v"(r) : "v"(x));
  return r;
}

__device__ __forceinline__ float fmax3(float a, float b, float c) {
  return fmaxf(fmaxf(a, b), c);  // clang fuses to v_max3_f32 on gfx9+
}

__device__ __forceinline__ void async_lds16(void* lds, const void* g) {
  // wave-uniform LDS base; lane i lands at base + 16*i (guide §5)
  __builtin_amdgcn_global_load_lds((const __attribute__((address_space(1))) uint32_t*)g,
                                   (__attribute__((address_space(3))) uint32_t*)lds,
                                   16, 0, 0);
}

// ---------------- prep: casts (8192 blocks) + weight transposes (768) ------
__global__ __launch_bounds__(256) void prep_k(const float* __restrict__ X,
                                              const float* __restrict__ E,
                                              const float* __restrict__ Wq,
                                              const float* __restrict__ Wo,
                                              const float* __restrict__ Wk,
                                              const float* __restrict__ Wv,
                                              ushort* __restrict__ Xb,
                                              ushort* __restrict__ Eb,
                                              ushort* __restrict__ Wqt,
                                              ushort* __restrict__ Wot,
                                              ushort* __restrict__ Wkvt) {
  __shared__ float t[64][65];
  const int bid = blockIdx.x;
  if (bid < 8192) {  // cast: 4096 blocks X, 4096 blocks E
    const float* s = (bid < 4096) ? X : E;
    ushort* d = (bid < 4096) ? Xb : Eb;
    int i = (bid & 4095) * 256 + threadIdx.x;
    float4 v = reinterpret_cast<const float4*>(s)[i];
    ushort4 o;
    o.x = bfbits(v.x); o.y = bfbits(v.y); o.z = bfbits(v.z); o.w = bfbits(v.w);
    reinterpret_cast<ushort4*>(d)[i] = o;
    return;
  }
  // weight transpose: W[R][C] f32 -> Wt[C][R] bf16 (R = 1024 always)
  const int w = bid - 8192;           // [0, 768)
  const int z = w >> 8, rem = w & 255;
  const int bx = rem & 15, by = rem >> 4;
  const float* src;
  ushort* dst;
  int C, c0;
  if (z == 0)      { src = Wq; dst = Wqt; C = 1024; c0 = bx * 64; }
  else if (z == 1) { src = Wo; dst = Wot; C = 1024; c0 = bx * 64; }
  else {
    if (bx >= 8) return;
    if (bx < 4) { src = Wk; dst = Wkvt; }
    else        { src = Wv; dst = Wkvt + 256 * 1024; }
    C = 256; c0 = (bx & 3) * 64;
  }
  const int r0 = by * 64;
  const int tx = threadIdx.x & 63, ty = threadIdx.x >> 6;
#pragma unroll
  for (int i = 0; i < 16; ++i) {
    int r = i * 4 + ty;
    t[r][tx] = src[(size_t)(r0 + r) * C + c0 + tx];
  }
  __syncthreads();
#pragma unroll
  for (int i = 0; i < 16; ++i) {
    int c = i * 4 + ty;
    dst[(size_t)(c0 + c) * 1024 + r0 + tx] = bfbits(t[tx][c]);
  }
}

// ------- GEMM mainloop: 128x64 tile, BK=64, 2-phase double-buffered --------
// LDS XOR-swizzle (16B chunk ^= row&7): linear dest, pre-swizzled global
// source, swizzled ds_read (rule #21).  One barrier per K-step.  48KB LDS.
__device__ __forceinline__ void gemm_mainloop(const ushort* __restrict__ A,
                                              const ushort* __restrict__ Bt,
                                              int m0, int n0, int K,
                                              char* sA, char* sB,
                                              f32x4 acc[4][2]) {
  const int lane = threadIdx.x & 63, wid = threadIdx.x >> 6;
  const int l15 = lane & 15, l4 = lane >> 4;
  const int wr = (wid >> 1) * 64, wc = (wid & 1) * 32;
  const int srow = lane >> 3;                    // row within 8-row chunk
  const int scc = (lane & 7) ^ (srow & 7);       // pre-swizzled global chunk
  const int rxr = l15 & 7;                       // read-side row xor

  const int nsteps = K >> 6;
  // prologue: stage K-step 0 into buf 0
#pragma unroll
  for (int j = 0; j < 4; ++j) {
    int c = wid * 4 + j;
    async_lds16(sA + c * 1024, A + (size_t)(m0 + c * 8 + srow) * K + scc * 8);
  }
#pragma unroll
  for (int j = 0; j < 2; ++j) {
    int c = wid * 2 + j;
    async_lds16(sB + c * 1024, Bt + (size_t)(n0 + c * 8 + srow) * K + scc * 8);
  }
  __syncthreads();

  int buf = 0;
  for (int s2 = 0; s2 < nsteps; ++s2) {
    if (s2 + 1 < nsteps) {  // stage next step into the other buffer
      const int k0 = (s2 + 1) * 64;
      char* dA = sA + (buf ^ 1) * 16384;
      char* dB = sB + (buf ^ 1) * 8192;
#pragma unroll
      for (int j = 0; j < 4; ++j) {
        int c = wid * 4 + j;
        async_lds16(dA + c * 1024, A + (size_t)(m0 + c * 8 + srow) * K + k0 + scc * 8);
      }
#pragma unroll
      for (int j = 0; j < 2; ++j) {
        int c = wid * 2 + j;
        async_lds16(dB + c * 1024, Bt + (size_t)(n0 + c * 8 + srow) * K + k0 + scc * 8);
      }
    }
    const char* aB = sA + buf * 16384;
    const char* bB = sB + buf * 8192;
    bf16x8 af[2][4], bfr[2][2];
#pragma unroll
    for (int mi = 0; mi < 4; ++mi) {
      const int row = wr + mi * 16 + l15;
#pragma unroll
      for (int kk = 0; kk < 2; ++kk)
        af[kk][mi] = *reinterpret_cast<const bf16x8*>(
            aB + row * 128 + (((l4 + kk * 4) ^ rxr) << 4));
    }
#pragma unroll
    for (int ni = 0; ni < 2; ++ni) {
      const int row = wc + ni * 16 + l15;
#pragma unroll
      for (int kk = 0; kk < 2; ++kk)
        bfr[kk][ni] = *reinterpret_cast<const bf16x8*>(
            bB + row * 128 + (((l4 + kk * 4) ^ rxr) << 4));
    }
#pragma unroll
    for (int kk = 0; kk < 2; ++kk)
#pragma unroll
      for (int mi = 0; mi < 4; ++mi)
#pragma unroll
        for (int ni = 0; ni < 2; ++ni)
          acc[mi][ni] = MFMA16(af[kk][mi], bfr[kk][ni], acc[mi][ni]);
    __syncthreads();  // drains vmcnt(0): next tile landed; buf reads done
    buf ^= 1;
  }
}

// ------- shared GEMM epilogue.  mode 0: f32 C+bias. mode 1: Q+RoPE+scale.
// mode 2: N=512, col<256 K+RoPE; col>=256 V -> transposed Vt. --------------
__device__ __forceinline__ void gemm_epilogue(f32x4 acc[4][2], int mode, int m0,
                                              int n0, const float* b0,
                                              const float* b1, float* Cf,
                                              ushort* U0, ushort* U1, int N) {
  const int lane = threadIdx.x & 63, wid = threadIdx.x >> 6;
  const int l15 = lane & 15, l4 = lane >> 4;
  const int wr = (wid >> 1) * 64, wc = (wid & 1) * 32;
#pragma unroll
  for (int ni = 0; ni < 2; ++ni) {
    const int col = n0 + wc + ni * 16 + l15;
    if (mode == 0) {
      const float bv = b0[col];
#pragma unroll
      for (int mi = 0; mi < 4; ++mi) {
        const int rowb = m0 + wr + mi * 16 + l4 * 4;
#pragma unroll
        for (int r = 0; r < 4; ++r)
          Cf[(size_t)(rowb + r) * N + col] = acc[mi][ni][r] + bv;
      }
    } else if (mode == 1) {
      const int h = col >> 6, d = col & 63, fi = d >> 1, odd = d & 1;
      const float div = __expf(-0.28782313662425572f * (float)fi);  // -ln(1e4)/32
      const float bv = b0[col];
#pragma unroll
      for (int mi = 0; mi < 4; ++mi) {
        const int rowb = m0 + wr + mi * 16 + l4 * 4;
#pragma unroll
        for (int r = 0; r < 4; ++r) {
          const int row = rowb + r, b = row >> 11, t = row & 2047;
          const float val = acc[mi][ni][r] + bv;
          const float prt = __shfl_xor(val, 1);  // partner column (d^1)
          float sn, cs;
          __sincosf((float)t * div, &sn, &cs);
          const float o = odd ? (prt * sn + val * cs) : (val * cs - prt * sn);
          U0[(((size_t)(b * Hc + h)) * TQc + t) * HDc + d] = bfbits(o * QSCALE);
        }
      }
    } else {
      if (col < 256) {  // K path: RoPE -> Kb[b][g][t][d]
        const int g = col >> 6, d = col & 63, fi = d >> 1, odd = d & 1;
        const float div = __expf(-0.28782313662425572f * (float)fi);
        const float bv = b0[col];
#pragma unroll
        for (int mi = 0; mi < 4; ++mi) {
          const int rowb = m0 + wr + mi * 16 + l4 * 4;
#pragma unroll
          for (int r = 0; r < 4; ++r) {
            const int row = rowb + r, b = row >> 11, t = row & 2047;
            const float val = acc[mi][ni][r] + bv;
            const float prt = __shfl_xor(val, 1);
            float sn, cs;
            __sincosf((float)t * div, &sn, &cs);
            const float o = odd ? (prt * sn + val * cs) : (val * cs - prt * sn);
            U0[(((size_t)(b * Gc + g)) * TKc + t) * HDc + d] = bfbits(o);
          }
        }
      } else {  // V path: transpose-write Vt[b][g][d][t]
        const int c2 = col - 256;
        const int g = c2 >> 6, d = c2 & 63;
        const float bv = b1[c2];
#pragma unroll
        for (int mi = 0; mi < 4; ++mi) {
          const int rowb = m0 + wr + mi * 16 + l4 * 4;
          const int b = rowb >> 11, t0 = rowb & 2047;
          ushort4 w;
          w.x = bfbits(acc[mi][ni][0] + bv);
          w.y = bfbits(acc[mi][ni][1] + bv);
          w.z = bfbits(acc[mi][ni][2] + bv);
          w.w = bfbits(acc[mi][ni][3] + bv);
          *reinterpret_cast<ushort4*>(
              &U1[(((size_t)(b * Gc + g)) * HDc + d) * TKc + t0]) = w;
        }
      }
    }
  }
}

// ------- Q-proj (tiles 0..511) + KV-proj (512..767), one launch ------------
// XCD-aware bijective block swizzle (768 % 8 == 0): each XCD gets a
// contiguous run of 96 tiles -> shared A-panels + weights stay L2-resident.
__global__ __launch_bounds__(256) void qkv_k(const ushort* __restrict__ Xb,
                                             const ushort* __restrict__ Eb,
                                             const ushort* __restrict__ Wqt,
                                             const ushort* __restrict__ Wkvt,
                                             const float* __restrict__ bq,
                                             const float* __restrict__ bk,
                                             const float* __restrict__ bv,
                                             ushort* __restrict__ Qb,
                                             ushort* __restrict__ Kb,
                                             ushort* __restrict__ Vt) {
  __shared__ __attribute__((aligned(16))) char smem[48 * 1024];
  const int bid0 = blockIdx.x;
  const int bid = (bid0 & 7) * 96 + (bid0 >> 3);  // T1 swizzle (bijective)
  const ushort *A, *Bt;
  const float *b0, *b1 = nullptr;
  ushort *U0, *U1 = nullptr;
  int mode, tb, tn;
  if (bid < 512) { A = Xb; Bt = Wqt; b0 = bq; U0 = Qb; mode = 1; tb = bid; tn = 16; }
  else { A = Eb; Bt = Wkvt; b0 = bk; b1 = bv; U0 = Kb; U1 = Vt; mode = 2; tb = bid - 512; tn = 8; }
  const int m0 = (tb / tn) * 128, n0 = (tb % tn) * 64;
  const f32x4 z = {0.f, 0.f, 0.f, 0.f};
  f32x4 acc[4][2] = {{z, z}, {z, z}, {z, z}, {z, z}};
  gemm_mainloop(A, Bt, m0, n0, 1024, smem, smem + 32768, acc);
  gemm_epilogue(acc, mode, m0, n0, b0, b1, nullptr, U0, U1, 0);
}

// ------- O-projection: out = Ob * Wot^T + bo (f32) -------------------------
__global__ __launch_bounds__(256) void oproj_k(const ushort* __restrict__ Ob,
                                               const ushort* __restrict__ Wot,
                                               const float* __restrict__ bo,
                                               float* __restrict__ out) {
  __shared__ __attribute__((aligned(16))) char smem[48 * 1024];
  const int bid0 = blockIdx.x;
  const int bid = (bid0 & 7) * 64 + (bid0 >> 3);  // T1 swizzle (512 % 8 == 0)
  const int m0 = (bid >> 4) * 128, n0 = (bid & 15) * 64;
  const f32x4 z = {0.f, 0.f, 0.f, 0.f};
  f32x4 acc[4][2] = {{z, z}, {z, z}, {z, z}, {z, z}};
  gemm_mainloop(Ob, Wot, m0, n0, 1024, smem, smem + 32768, acc);
  gemm_epilogue(acc, 0, m0, n0, bo, nullptr, out, nullptr, nullptr, 1024);
}

// ------- flash attention, LDS-staged K/V, swapped-QK^T, log2 softmax -------
// Qb[b][h][t][64] (pre-scaled by 0.125*log2e), Kb[b][g][t][64], Vt[b][g][64][t].
// 1024 thr = 16 waves x 16 q-rows (256 q-rows/block), KVBLK=64, grid 256.
// Decode: bid&7 = (b,g); pos = bid>>3 in 0..31; h = g*4 + (pos>>3);
//         q0 = (pos&7)*256 + wid*16  (max 7*256+15*16+16 = 2048, exact).
// Double-buffered K/V, SPLIT staging: waves 0-7 stage K rows (wid&7)*8..+7,
// waves 8-15 stage V rows likewise -> 1 global_load_lds per wave per tile.
// l-sum via ones-MFMA: acc1 = P·1 lands in the epilogue row layout.
__global__ __launch_bounds__(1024, 4) void attn_k(const ushort* __restrict__ Qg,
                                                  const ushort* __restrict__ Kg,
                                                  const ushort* __restrict__ Vg,
                                                  ushort* __restrict__ Ob) {
  __shared__ __attribute__((aligned(16))) char smem[64 * 1024];
  const int lane = threadIdx.x & 63, wid = threadIdx.x >> 6;  // wid 0..15
  const int l15 = lane & 15, l4 = lane >> 4;
  // XCD-aware decode: bid&7 = (b,g) group -> each XCD L2 caches ONE group's K/V
  const int bid = blockIdx.x;  // 256 blocks
  const int bg = bid & 7, pos = bid >> 3;      // pos 0..31
  const int b = bg >> 2, g = bg & 3;
  const int h = g * 4 + (pos >> 3);            // 4 heads per group
  const int q0 = (pos & 7) * 256 + wid * 16;   // 16 q-rows per wave
  const ushort* Qp = Qg + ((size_t)(b * Hc + h)) * TQc * HDc;
  const ushort* Kp = Kg + ((size_t)(b * Gc + g)) * TKc * HDc;
  const ushort* Vp = Vg + ((size_t)(b * Gc + g)) * HDc * TKc;
  // LDS map: K dbuf [2][8192], V dbuf [2][8192], P [16][2048]
  char* sK = smem;                          // 0   .. 16K
  char* sV = smem + 16384;                  // 16K .. 32K
  char* pb = smem + 32768 + wid * 2048;     // per-wave P tile [16][64] bf16
  const int rx = (l15 & 7) << 4;            // P-row swizzle
  const int swz = l15 & 7;                  // K/V fragment chunk swizzle

  // staging: waves 0-7 stage K (1KB each), waves 8-15 stage V (1KB each)
  const int wkv = wid & 7;
  const int sr = wkv * 8 + (lane >> 3);              // tile row this lane fills
  const int sc = (lane & 7) ^ ((lane >> 3) & 7);     // pre-swizzled src chunk
  const bool isK = (wid < 8);                        // wave-uniform
  const char* srcN = isK ? (const char*)Kp + (size_t)sr * 128 + sc * 16
                         : (const char*)Vp + (size_t)sr * (TKc * 2) + sc * 16;
  const size_t srcStep = isK ? 8192 : 128;
  char* dstBase = (isK ? sK : sV) + wkv * 1024;

  // Q (B operand): col n=l15 -> q=q0+l15, k=l4*8+j -> d
  bf16x8 bq0 = *reinterpret_cast<const bf16x8*>(Qp + (size_t)(q0 + l15) * HDc + l4 * 8);
  bf16x8 bq1 = *reinterpret_cast<const bf16x8*>(Qp + (size_t)(q0 + l15) * HDc + 32 + l4 * 8);

  bf16x8 vones;
#pragma unroll
  for (int i = 0; i < 8; ++i) vones[i] = (__bf16)1.0f;

  float m = -INFINITY;
  const f32x4 z = {0.f, 0.f, 0.f, 0.f};
  f32x4 accO[4] = {z, z, z, z};
  f32x4 acc1 = z;  // softmax denominator: rows q=l4*4+r, all cols equal

  constexpr int NT = TKc / 64;
  // prologue: stage tile 0 into buffer 0
  async_lds16(dstBase, srcN);
  srcN += srcStep;
  __syncthreads();

  int buf = 0;
  for (int kt = 0; kt < NT; ++kt) {
    if (kt + 1 < NT) {  // issue next-tile load; completes under compute
      async_lds16(dstBase + (buf ^ 1) * 8192, srcN);
      srcN += srcStep;
    }
    const char* sKb = sK + buf * 8192;
    const char* sVb = sV + buf * 8192;

    // QK^T: A = K[key=nf*16+l15][d], B = Q -> S^T[key][q=l15]  (log2 domain)
    f32x4 s[4] = {z, z, z, z};
#pragma unroll
    for (int nf = 0; nf < 4; ++nf) {
      const char* krow = sKb + (nf * 16 + l15) * 128;
      bf16x8 kf0 = *reinterpret_cast<const bf16x8*>(krow + ((l4 ^ swz) << 4));
      bf16x8 kf1 = *reinterpret_cast<const bf16x8*>(krow + (((4 + l4) ^ swz) << 4));
      s[nf] = MFMA16(kf0, bq0, s[nf]);
      s[nf] = MFMA16(kf1, bq1, s[nf]);
    }
    // V fragments from LDS: B[k=key][n=d]:  va[df][kk] = V^T tile row d
    bf16x8 va[4][2];
#pragma unroll
    for (int df = 0; df < 4; ++df) {
      const char* vrow = sVb + (df * 16 + l15) * 128;
      va[df][0] = *reinterpret_cast<const bf16x8*>(vrow + ((l4 ^ swz) << 4));
      va[df][1] = *reinterpret_cast<const bf16x8*>(vrow + (((4 + l4) ^ swz) << 4));
    }

    // ---- lane-local softmax (one q-row per lane, log2 domain) ----
    float pm = fmax3(fmax3(s[0][0], s[0][1], s[0][2]),
                     fmax3(s[0][3], s[1][0], s[1][1]),
                     fmax3(s[1][2], s[1][3], s[2][0]));
    pm = fmax3(pm,
               fmax3(s[2][1], s[2][2], s[2][3]),
               fmax3(s[3][0], s[3][1], fmaxf(s[3][2], s[3][3])));
    pm = fmaxf(pm, __shfl_xor(pm, 16));
    pm = fmaxf(pm, __shfl_xor(pm, 32));
    if (!__all(pm - m <= 11.5f)) {  // T13 defer-max (log2 units)
      float mn = fmaxf(m, pm);
      float sc2 = fexp2(m - mn);
      m = mn;
      acc1 *= sc2;
#pragma unroll
      for (int df = 0; df < 4; ++df) accO[df] *= sc2;
    }
#pragma unroll
    for (int nf = 0; nf < 4; ++nf)
#pragma unroll
      for (int r = 0; r < 4; ++r)
        s[nf][r] = fexp2(s[nf][r] - m);

    // ---- P -> per-wave LDS (row q=l15): 4x ds_write_b64, swizzled ----
#pragma unroll
    for (int nf = 0; nf < 4; ++nf) {
      bf16x4v pv;
      pv[0] = (__bf16)s[nf][0];
      pv[1] = (__bf16)s[nf][1];
      pv[2] = (__bf16)s[nf][2];
      pv[3] = (__bf16)s[nf][3];
      *reinterpret_cast<uint2*>(pb + l15 * 128 + ((nf * 32 + l4 * 8) ^ rx)) =
          __builtin_bit_cast(uint2, pv);
    }
    asm volatile("" ::: "memory");  // order P writes before P reads (TBAA insurance)
    // ---- PV: A = P[q=l15][k=key], B = V^T[key][d]; plus l = P·1 ----
    bf16x8 ap0 = *reinterpret_cast<const bf16x8*>(pb + l15 * 128 + ((l4 * 16) ^ rx));
    bf16x8 ap1 = *reinterpret_cast<const bf16x8*>(pb + l15 * 128 + ((64 + l4 * 16) ^ rx));
#pragma unroll
    for (int df = 0; df < 4; ++df)
      accO[df] = MFMA16(ap1, va[df][1], MFMA16(ap0, va[df][0], accO[df]));
    acc1 = MFMA16(ap1, vones, MFMA16(ap0, vones, acc1));

    __syncthreads();  // drains vmcnt: next tile landed; all waves done reading
    buf ^= 1;
  }

  // epilogue: lane holds O[q=q0+l4*4+r][d=df*16+l15]; acc1[r] = l for same row
  float inv[4];
#pragma unroll
  for (int r = 0; r < 4; ++r) inv[r] = 1.f / acc1[r];
#pragma unroll
  for (int df = 0; df < 4; ++df)
#pragma unroll
    for (int r = 0; r < 4; ++r) {
      int row = q0 + l4 * 4 + r;
      int col = h * HDc + df * 16 + l15;
      Ob[((size_t)b * TQc + row) * Dc + col] = bfbits(accO[df][r] * inv[r]);
    }
}

// ---------------------------------------------------------------------------
extern "C" void kernel_launch(void* const* d_in, const int* in_sizes, int n_in,
                              void* d_out, int out_size, void* d_ws, size_t ws_size,
                              hipStream_t stream) {
  const float* X  = (const float*)d_in[0];
  const float* E  = (const float*)d_in[1];
  const float* Wq = (const float*)d_in[2];
  const float* bq = (const float*)d_in[3];
  const float* Wk = (const float*)d_in[4];
  const float* bk = (const float*)d_in[5];
  const float* Wv = (const float*)d_in[6];
  const float* bv = (const float*)d_in[7];
  const float* Wo = (const float*)d_in[8];
  const float* bo = (const float*)d_in[9];
  float* out = (float*)d_out;
  char* ws = (char*)d_ws;

  const size_t MB = 1ull << 20;
  if (ws_size < 42 * MB) return;  // tripwire: reproduces stub failure signature

  ushort* Xb   = (ushort*)(ws + 0 * MB);   // [4096][1024] bf16
  ushort* Eb   = (ushort*)(ws + 8 * MB);   // [4096][1024]
  ushort* Wqt  = (ushort*)(ws + 16 * MB);  // [1024][1024]
  ushort* Wkvt = (ushort*)(ws + 18 * MB);  // [512][1024] (Wk^T | Wv^T)
  ushort* Wot  = (ushort*)(ws + 19 * MB);  // [1024][1024]
  ushort* Qb   = (ushort*)(ws + 21 * MB);  // [2][16][2048][64]
  ushort* Kb   = (ushort*)(ws + 29 * MB);  // [2][4][2048][64]
  ushort* Vt   = (ushort*)(ws + 31 * MB);  // [2][4][64][2048]
  ushort* Ob   = (ushort*)(ws + 33 * MB);  // [2][2048][1024]

  // 1. casts + weight transposes
  prep_k<<<dim3(8960), 256, 0, stream>>>(X, E, Wq, Wo, Wk, Wv, Xb, Eb, Wqt, Wot, Wkvt);
  // 2. Q-proj (+RoPE+scale) and KV-proj (K+RoPE, V^T) concurrently
  qkv_k<<<dim3(768), 256, 0, stream>>>(Xb, Eb, Wqt, Wkvt, bq, bk, bv, Qb, Kb, Vt);
  // 3. attention -> Ob
  attn_k<<<dim3(256), dim3(1024), 0, stream>>>(Qb, Kb, Vt, Ob);
  // 4. output projection -> out (f32)
  oproj_k<<<dim3(512), 256, 0, stream>>>(Ob, Wot, bo, out);
}